// Round 1
// baseline (7397.990 us; speedup 1.0000x reference)
//
#include <hip/hip_runtime.h>
#include <hip/hip_bf16.h>
#include <math.h>

#define BB 32
#define SS 65536
#define CC 20
#define NM 16
#define HH 128

using short8  = __attribute__((ext_vector_type(8))) short;
using floatx4 = __attribute__((ext_vector_type(4))) float;

__device__ __forceinline__ short f2bf(float f) {
    union { float f; unsigned u; } v; v.f = f;
    unsigned u = v.u;
    unsigned r = (u + 0x7FFFu + ((u >> 16) & 1u)) >> 16;   // RNE
    return (short)r;
}

// ---------------- k_prep: 1/max(point_data) ----------------
__global__ __launch_bounds__(256) void k_prep(const float* __restrict__ pd, float* __restrict__ invmax) {
    __shared__ float red[256];
    int t = threadIdx.x;
    float m = -1e30f;
    for (int i = t; i < SS; i += 256) m = fmaxf(m, pd[i]);
    red[t] = m; __syncthreads();
    for (int off = 128; off > 0; off >>= 1) {
        if (t < off) red[t] = fmaxf(red[t], red[t + off]);
        __syncthreads();
    }
    if (t == 0) invmax[0] = 1.0f / red[0];
}

// ---------------- k_basis: bf16 basisT[32][S]; rows 0-15 cos, 16-31 sin ----
__global__ __launch_bounds__(256) void k_basis(unsigned short* __restrict__ basisT) {
    int s = blockIdx.x * 256 + threadIdx.x;
    #pragma unroll
    for (int m = 0; m < NM; ++m) {
        unsigned t = ((unsigned)s * (unsigned)m) & 65535u;   // exact angle reduction
        float ang = (float)t * (float)(6.283185307179586 / 65536.0);
        float sn, cs;
        sincosf(ang, &sn, &cs);
        basisT[(size_t)m * SS + s]        = (unsigned short)f2bf(cs);
        basisT[(size_t)(16 + m) * SS + s] = (unsigned short)f2bf(sn);
    }
}

// ---------------- k_fc0: h[b][c][s] ----------------
__global__ __launch_bounds__(256) void k_fc0(const float* __restrict__ x, const float* __restrict__ pd,
                                             const float* __restrict__ w, const float* __restrict__ bias,
                                             const float* __restrict__ invmax, float* __restrict__ h) {
    __shared__ float lw[2 * CC], lb[CC];
    int tid = threadIdx.x;
    if (tid < 2 * CC) lw[tid] = w[tid];
    if (tid < CC) lb[tid] = bias[tid];
    __syncthreads();
    int s = blockIdx.x * 256 + tid;
    int b = blockIdx.y;
    float xv = x[(size_t)b * SS + s];
    float g  = pd[s] * invmax[0];
    float* hp = h + (size_t)b * CC * SS + s;
    #pragma unroll
    for (int c = 0; c < CC; ++c)
        hp[(size_t)c * SS] = xv * lw[c] + g * lw[CC + c] + lb[c];
}

// ---------------- k_dft: X partials via MFMA bf16 GEMM ----------------
// grid (32 k-parts, 40 m-tiles), 256 thr. Xp[part][row(640)][col(32)]
__global__ __launch_bounds__(256) void k_dft(const float* __restrict__ h,
                                             const unsigned short* __restrict__ basisT,
                                             float* __restrict__ Xp) {
    int part = blockIdx.x, mtile = blockIdx.y;
    int tid = threadIdx.x;
    int wave = tid >> 6, lane = tid & 63;
    int mrow = lane & 15, quad = lane >> 4;
    int row = mtile * 16 + mrow;
    int kbase = part * 2048 + wave * 512 + quad * 8;
    const float* ap = h + (size_t)row * SS + kbase;
    const unsigned short* bp0 = basisT + (size_t)mrow * SS + kbase;
    const unsigned short* bp1 = basisT + (size_t)(16 + mrow) * SS + kbase;
    floatx4 acc0 = {0.f, 0.f, 0.f, 0.f}, acc1 = {0.f, 0.f, 0.f, 0.f};
    #pragma unroll 2
    for (int kk = 0; kk < 16; ++kk) {
        const float4* af = (const float4*)ap;
        float4 a0 = af[0], a1 = af[1];
        short8 afr;
        afr[0] = f2bf(a0.x); afr[1] = f2bf(a0.y); afr[2] = f2bf(a0.z); afr[3] = f2bf(a0.w);
        afr[4] = f2bf(a1.x); afr[5] = f2bf(a1.y); afr[6] = f2bf(a1.z); afr[7] = f2bf(a1.w);
        short8 b0 = *(const short8*)bp0;
        short8 b1 = *(const short8*)bp1;
        acc0 = __builtin_amdgcn_mfma_f32_16x16x32_bf16(afr, b0, acc0, 0, 0, 0);
        acc1 = __builtin_amdgcn_mfma_f32_16x16x32_bf16(afr, b1, acc1, 0, 0, 0);
        ap += 32; bp0 += 32; bp1 += 32;
    }
    __shared__ float red[4][512];
    #pragma unroll
    for (int r = 0; r < 4; ++r) {
        red[wave][0 * 256 + r * 64 + lane] = acc0[r];
        red[wave][1 * 256 + r * 64 + lane] = acc1[r];
    }
    __syncthreads();
    for (int idx = tid; idx < 512; idx += 256) {
        float v = red[0][idx] + red[1][idx] + red[2][idx] + red[3][idx];
        int nt = idx >> 8, r = (idx >> 6) & 3, ln = idx & 63;
        int orow = ((ln >> 4) << 2) + r;          // D row = quad*4+reg
        int col  = nt * 16 + (ln & 15);           // D col = lane&15
        Xp[((size_t)part * 640 + mtile * 16 + orow) * 32 + col] = v;
    }
}

// ---------------- k_mix: partial-sum + complex mixing -> irfft coefs --------
__global__ __launch_bounds__(320) void k_mix(const float* __restrict__ Xp,
                                             const float* __restrict__ wre, const float* __restrict__ wim,
                                             float* __restrict__ cA, float* __restrict__ cB) {
    int b = blockIdx.x, tid = threadIdx.x;
    __shared__ float PQ[640];                     // [i][col] : col<16 P(cos), col>=16 Q(sin)
    for (int idx = tid; idx < 640; idx += 320) {
        int i = idx >> 5, col = idx & 31;
        const float* p = Xp + ((size_t)b * CC + i) * 32 + col;
        float s = 0.f;
        #pragma unroll 8
        for (int part = 0; part < 32; ++part) s += p[(size_t)part * 640 * 32];
        PQ[idx] = s;
    }
    __syncthreads();
    int o = tid / 16, m = tid & 15;
    float reY = 0.f, imY = 0.f;
    #pragma unroll
    for (int i = 0; i < CC; ++i) {
        float P = PQ[i * 32 + m], Q = PQ[i * 32 + 16 + m];
        float wr = wre[(size_t)(i * CC + o) * NM + m];
        float wi = wim[(size_t)(i * CC + o) * NM + m];
        reY += P * wr + Q * wi;                   // X = P - iQ
        imY += P * wi - Q * wr;
    }
    const float invS = 1.0f / (float)SS;
    float a, bb;
    if (m == 0) { a = reY * invS; bb = 0.0f; }    // irfft drops Im(DC)
    else        { a = 2.0f * reY * invS; bb = -2.0f * imY * invS; }
    cA[(size_t)(b * CC + o) * NM + m] = a;
    cB[(size_t)(b * CC + o) * NM + m] = bb;
}

// ---------------- k_point: h = act(spectral + 1x1conv + bias), in place -----
__global__ __launch_bounds__(256) void k_point(float* __restrict__ h,
                                               const float* __restrict__ ww, const float* __restrict__ wb,
                                               const float* __restrict__ cA, const float* __restrict__ cB,
                                               int do_gelu) {
    __shared__ float lww[CC * CC], lwb[CC], lA[CC * NM], lB[CC * NM];
    int tid = threadIdx.x;
    int b = blockIdx.y;
    for (int i = tid; i < CC * CC; i += 256) lww[i] = ww[i];
    if (tid < CC) lwb[tid] = wb[tid];
    for (int i = tid; i < CC * NM; i += 256) { lA[i] = cA[b * CC * NM + i]; lB[i] = cB[b * CC * NM + i]; }
    __syncthreads();
    int s = blockIdx.x * 256 + tid;
    float* hp = h + (size_t)b * CC * SS + s;
    float hv[CC];
    #pragma unroll
    for (int c = 0; c < CC; ++c) hv[c] = hp[(size_t)c * SS];
    float acc[CC];
    #pragma unroll
    for (int o = 0; o < CC; ++o) acc[o] = lwb[o];
    #pragma unroll
    for (int c = 0; c < CC; ++c) {
        float hc = hv[c];
        #pragma unroll
        for (int o = 0; o < CC; ++o) acc[o] += lww[o * CC + c] * hc;
    }
    // spectral term: phasor recurrence from theta_1 = pi * (s/32768)
    float u = (float)s * (1.0f / 32768.0f);
    float s1, c1;
    sincospif(u, &s1, &c1);
    float cm = 1.0f, sm = 0.0f;
    #pragma unroll
    for (int m = 0; m < NM; ++m) {
        #pragma unroll
        for (int o = 0; o < CC; ++o)
            acc[o] += lA[o * NM + m] * cm + lB[o * NM + m] * sm;
        float cn = cm * c1 - sm * s1;
        sm = sm * c1 + cm * s1;
        cm = cn;
    }
    #pragma unroll
    for (int o = 0; o < CC; ++o) {
        float v = acc[o];
        if (do_gelu) v = 0.5f * v * (1.0f + erff(v * 0.7071067811865476f));
        hp[(size_t)o * SS] = v;
    }
}

// ---------------- k_final: fc1 + gelu + fc2 ----------------
__global__ __launch_bounds__(256) void k_final(const float* __restrict__ h,
                                               const float* __restrict__ w1, const float* __restrict__ b1,
                                               const float* __restrict__ w2, const float* __restrict__ b2,
                                               float* __restrict__ out) {
    __shared__ float lw1[CC * HH], lb1[HH], lw2[HH];
    int tid = threadIdx.x;
    for (int i = tid; i < CC * HH; i += 256) lw1[i] = w1[i];
    if (tid < HH) { lb1[tid] = b1[tid]; lw2[tid] = w2[tid]; }
    __syncthreads();
    int b = blockIdx.y;
    int s = blockIdx.x * 256 + tid;
    const float* hp = h + (size_t)b * CC * SS + s;
    float hv[CC];
    #pragma unroll
    for (int c = 0; c < CC; ++c) hv[c] = hp[(size_t)c * SS];
    float acc = b2[0];
    for (int j = 0; j < HH; ++j) {
        float t = lb1[j];
        #pragma unroll
        for (int c = 0; c < CC; ++c) t += hv[c] * lw1[c * HH + j];
        t = 0.5f * t * (1.0f + erff(t * 0.7071067811865476f));
        acc += t * lw2[j];
    }
    out[(size_t)b * SS + s] = acc;
}

extern "C" void kernel_launch(void* const* d_in, const int* in_sizes, int n_in,
                              void* d_out, int out_size, void* d_ws, size_t ws_size,
                              hipStream_t stream) {
    (void)in_sizes; (void)n_in; (void)out_size; (void)ws_size;
    const float* x    = (const float*)d_in[0];
    const float* pd   = (const float*)d_in[1];
    const float* fc0w = (const float*)d_in[2];
    const float* fc0b = (const float*)d_in[3];
    const float* fc1w = (const float*)d_in[4];
    const float* fc1b = (const float*)d_in[5];
    const float* fc2w = (const float*)d_in[6];
    const float* fc2b = (const float*)d_in[7];

    char* ws = (char*)d_ws;
    float* h = (float*)ws;
    size_t off = (size_t)BB * CC * SS * 4;                       // 167.8 MB
    unsigned short* basisT = (unsigned short*)(ws + off); off += (size_t)32 * SS * 2;   // 4 MB
    float* Xp = (float*)(ws + off); off += (size_t)32 * 640 * 32 * 4;                   // 2.6 MB
    float* cA = (float*)(ws + off); off += (size_t)BB * CC * NM * 4;
    float* cB = (float*)(ws + off); off += (size_t)BB * CC * NM * 4;
    float* invmax = (float*)(ws + off); off += 256;

    dim3 gBS(SS / 256, BB);

    k_prep<<<1, 256, 0, stream>>>(pd, invmax);
    k_basis<<<SS / 256, 256, 0, stream>>>(basisT);
    k_fc0<<<gBS, 256, 0, stream>>>(x, pd, fc0w, fc0b, invmax, h);

    for (int l = 0; l < 4; ++l) {
        const float* wre = (const float*)d_in[8 + 4 * l];
        const float* wim = (const float*)d_in[9 + 4 * l];
        const float* ww  = (const float*)d_in[10 + 4 * l];
        const float* wb  = (const float*)d_in[11 + 4 * l];
        k_dft<<<dim3(32, 40), 256, 0, stream>>>(h, basisT, Xp);
        k_mix<<<BB, 320, 0, stream>>>(Xp, wre, wim, cA, cB);
        k_point<<<gBS, 256, 0, stream>>>(h, ww, wb, cA, cB, (l < 3) ? 1 : 0);
    }
    k_final<<<gBS, 256, 0, stream>>>(h, fc1w, fc1b, fc2w, fc2b, (float*)d_out);
}

// Round 2
// 2700.811 us; speedup vs baseline: 2.7392x; 2.7392x over previous
//
#include <hip/hip_runtime.h>
#include <hip/hip_bf16.h>
#include <math.h>

#define BB 32
#define SS 65536
#define CC 20
#define NM 16
#define HH 128

using short8  = __attribute__((ext_vector_type(8))) short;
using floatx4 = __attribute__((ext_vector_type(4))) float;

__device__ __forceinline__ short f2bf(float f) {
    union { float f; unsigned u; } v; v.f = f;
    unsigned u = v.u;
    unsigned r = (u + 0x7FFFu + ((u >> 16) & 1u)) >> 16;   // RNE
    return (short)r;
}

// ---------------- k_prep: 1/max(point_data) ----------------
__global__ __launch_bounds__(256) void k_prep(const float* __restrict__ pd, float* __restrict__ invmax) {
    __shared__ float red[256];
    int t = threadIdx.x;
    float m = -1e30f;
    for (int i = t; i < SS; i += 256) m = fmaxf(m, pd[i]);
    red[t] = m; __syncthreads();
    for (int off = 128; off > 0; off >>= 1) {
        if (t < off) red[t] = fmaxf(red[t], red[t + off]);
        __syncthreads();
    }
    if (t == 0) invmax[0] = 1.0f / red[0];
}

// ---------------- k_basis: bf16 basisT[32][S]; rows 0-15 cos, 16-31 sin ----
__global__ __launch_bounds__(256) void k_basis(unsigned short* __restrict__ basisT) {
    int s = blockIdx.x * 256 + threadIdx.x;
    #pragma unroll
    for (int m = 0; m < NM; ++m) {
        unsigned t = ((unsigned)s * (unsigned)m) & 65535u;   // exact angle reduction
        float ang = (float)t * (float)(6.283185307179586 / 65536.0);
        float sn, cs;
        sincosf(ang, &sn, &cs);
        basisT[(size_t)m * SS + s]        = (unsigned short)f2bf(cs);
        basisT[(size_t)(16 + m) * SS + s] = (unsigned short)f2bf(sn);
    }
}

// ---------------- k_fc0: h[b][c][s] ----------------
__global__ __launch_bounds__(256) void k_fc0(const float* __restrict__ x, const float* __restrict__ pd,
                                             const float* __restrict__ w, const float* __restrict__ bias,
                                             const float* __restrict__ invmax, float* __restrict__ h) {
    __shared__ float lw[2 * CC], lb[CC];
    int tid = threadIdx.x;
    if (tid < 2 * CC) lw[tid] = w[tid];
    if (tid < CC) lb[tid] = bias[tid];
    __syncthreads();
    int s = blockIdx.x * 256 + tid;
    int b = blockIdx.y;
    float xv = x[(size_t)b * SS + s];
    float g  = pd[s] * invmax[0];
    float* hp = h + (size_t)b * CC * SS + s;
    #pragma unroll
    for (int c = 0; c < CC; ++c)
        hp[(size_t)c * SS] = xv * lw[c] + g * lw[CC + c] + lb[c];
}

// ---------------- k_dft: X partials via MFMA bf16 GEMM ----------------
// grid (32 k-parts, 40 m-tiles), 256 thr. Xp[part][row(640)][col(32)]
__global__ __launch_bounds__(256) void k_dft(const float* __restrict__ h,
                                             const unsigned short* __restrict__ basisT,
                                             float* __restrict__ Xp) {
    int part = blockIdx.x, mtile = blockIdx.y;
    int tid = threadIdx.x;
    int wave = tid >> 6, lane = tid & 63;
    int mrow = lane & 15, quad = lane >> 4;
    int row = mtile * 16 + mrow;
    int kbase = part * 2048 + wave * 512 + quad * 8;
    const float* ap = h + (size_t)row * SS + kbase;
    const unsigned short* bp0 = basisT + (size_t)mrow * SS + kbase;
    const unsigned short* bp1 = basisT + (size_t)(16 + mrow) * SS + kbase;
    floatx4 acc0 = {0.f, 0.f, 0.f, 0.f}, acc1 = {0.f, 0.f, 0.f, 0.f};
    #pragma unroll 2
    for (int kk = 0; kk < 16; ++kk) {
        const float4* af = (const float4*)ap;
        float4 a0 = af[0], a1 = af[1];
        short8 afr;
        afr[0] = f2bf(a0.x); afr[1] = f2bf(a0.y); afr[2] = f2bf(a0.z); afr[3] = f2bf(a0.w);
        afr[4] = f2bf(a1.x); afr[5] = f2bf(a1.y); afr[6] = f2bf(a1.z); afr[7] = f2bf(a1.w);
        short8 b0 = *(const short8*)bp0;
        short8 b1 = *(const short8*)bp1;
        acc0 = __builtin_amdgcn_mfma_f32_16x16x32_bf16(afr, b0, acc0, 0, 0, 0);
        acc1 = __builtin_amdgcn_mfma_f32_16x16x32_bf16(afr, b1, acc1, 0, 0, 0);
        ap += 32; bp0 += 32; bp1 += 32;
    }
    __shared__ float red[4][512];
    #pragma unroll
    for (int r = 0; r < 4; ++r) {
        red[wave][0 * 256 + r * 64 + lane] = acc0[r];
        red[wave][1 * 256 + r * 64 + lane] = acc1[r];
    }
    __syncthreads();
    for (int idx = tid; idx < 512; idx += 256) {
        float v = red[0][idx] + red[1][idx] + red[2][idx] + red[3][idx];
        int nt = idx >> 8, r = (idx >> 6) & 3, ln = idx & 63;
        int orow = ((ln >> 4) << 2) + r;          // D row = quad*4+reg
        int col  = nt * 16 + (ln & 15);           // D col = lane&15
        Xp[((size_t)part * 640 + mtile * 16 + orow) * 32 + col] = v;
    }
}

// ---------------- k_mix: partial-sum + complex mixing -> irfft coefs --------
__global__ __launch_bounds__(320) void k_mix(const float* __restrict__ Xp,
                                             const float* __restrict__ wre, const float* __restrict__ wim,
                                             float* __restrict__ cA, float* __restrict__ cB) {
    int b = blockIdx.x, tid = threadIdx.x;
    __shared__ float PQ[640];                     // [i][col] : col<16 P(cos), col>=16 Q(sin)
    for (int idx = tid; idx < 640; idx += 320) {
        int i = idx >> 5, col = idx & 31;
        const float* p = Xp + ((size_t)b * CC + i) * 32 + col;
        float s = 0.f;
        #pragma unroll 8
        for (int part = 0; part < 32; ++part) s += p[(size_t)part * 640 * 32];
        PQ[idx] = s;
    }
    __syncthreads();
    int o = tid / 16, m = tid & 15;
    float reY = 0.f, imY = 0.f;
    #pragma unroll
    for (int i = 0; i < CC; ++i) {
        float P = PQ[i * 32 + m], Q = PQ[i * 32 + 16 + m];
        float wr = wre[(size_t)(i * CC + o) * NM + m];
        float wi = wim[(size_t)(i * CC + o) * NM + m];
        reY += P * wr + Q * wi;                   // X = P - iQ
        imY += P * wi - Q * wr;
    }
    const float invS = 1.0f / (float)SS;
    float a, bb;
    if (m == 0) { a = reY * invS; bb = 0.0f; }    // irfft drops Im(DC)
    else        { a = 2.0f * reY * invS; bb = -2.0f * imY * invS; }
    cA[(size_t)(b * CC + o) * NM + m] = a;
    cB[(size_t)(b * CC + o) * NM + m] = bb;
}

// ---------------- k_point: h = act(spectral + 1x1conv + bias), in place -----
// Restructured vs R0: per-o scalar accumulator + immediate store; phasors
// precomputed once. Live set ~70 VGPR (R0 version spilled: VGPR=256,
// 6.6 GB scratch traffic/dispatch).
__global__ __launch_bounds__(256, 4) void k_point(float* __restrict__ h,
                                               const float* __restrict__ ww, const float* __restrict__ wb,
                                               const float* __restrict__ cA, const float* __restrict__ cB,
                                               int do_gelu) {
    __shared__ float lww[CC * CC], lwb[CC], lA[CC * NM], lB[CC * NM];
    int tid = threadIdx.x;
    int b = blockIdx.y;
    for (int i = tid; i < CC * CC; i += 256) lww[i] = ww[i];
    if (tid < CC) lwb[tid] = wb[tid];
    for (int i = tid; i < CC * NM; i += 256) { lA[i] = cA[b * CC * NM + i]; lB[i] = cB[b * CC * NM + i]; }
    __syncthreads();
    int s = blockIdx.x * 256 + tid;
    float* hp = h + (size_t)b * CC * SS + s;

    // phasors: theta_m = 2*pi*m*s/S, via recurrence from theta_1
    float u = (float)s * (1.0f / 32768.0f);
    float s1, c1;
    sincospif(u, &s1, &c1);
    float cm[NM], sm[NM];
    cm[0] = 1.0f; sm[0] = 0.0f;
    #pragma unroll
    for (int m = 1; m < NM; ++m) {
        cm[m] = cm[m - 1] * c1 - sm[m - 1] * s1;
        sm[m] = sm[m - 1] * c1 + cm[m - 1] * s1;
    }

    float hv[CC];
    #pragma unroll
    for (int c = 0; c < CC; ++c) hv[c] = hp[(size_t)c * SS];

    #pragma unroll 2
    for (int o = 0; o < CC; ++o) {
        float a = lwb[o];
        #pragma unroll
        for (int c = 0; c < CC; ++c) a += lww[o * CC + c] * hv[c];
        #pragma unroll
        for (int m = 0; m < NM; ++m)
            a += lA[o * NM + m] * cm[m] + lB[o * NM + m] * sm[m];
        if (do_gelu) a = 0.5f * a * (1.0f + erff(a * 0.7071067811865476f));
        hp[(size_t)o * SS] = a;
    }
}

// ---------------- k_final: fc1 + gelu + fc2 ----------------
__global__ __launch_bounds__(256) void k_final(const float* __restrict__ h,
                                               const float* __restrict__ w1, const float* __restrict__ b1,
                                               const float* __restrict__ w2, const float* __restrict__ b2,
                                               float* __restrict__ out) {
    __shared__ float lw1[CC * HH], lb1[HH], lw2[HH];
    int tid = threadIdx.x;
    for (int i = tid; i < CC * HH; i += 256) lw1[i] = w1[i];
    if (tid < HH) { lb1[tid] = b1[tid]; lw2[tid] = w2[tid]; }
    __syncthreads();
    int b = blockIdx.y;
    int s = blockIdx.x * 256 + tid;
    const float* hp = h + (size_t)b * CC * SS + s;
    float hv[CC];
    #pragma unroll
    for (int c = 0; c < CC; ++c) hv[c] = hp[(size_t)c * SS];
    float acc = b2[0];
    for (int j = 0; j < HH; ++j) {
        float t = lb1[j];
        #pragma unroll
        for (int c = 0; c < CC; ++c) t += hv[c] * lw1[c * HH + j];
        t = 0.5f * t * (1.0f + erff(t * 0.7071067811865476f));
        acc += t * lw2[j];
    }
    out[(size_t)b * SS + s] = acc;
}

extern "C" void kernel_launch(void* const* d_in, const int* in_sizes, int n_in,
                              void* d_out, int out_size, void* d_ws, size_t ws_size,
                              hipStream_t stream) {
    (void)in_sizes; (void)n_in; (void)out_size; (void)ws_size;
    const float* x    = (const float*)d_in[0];
    const float* pd   = (const float*)d_in[1];
    const float* fc0w = (const float*)d_in[2];
    const float* fc0b = (const float*)d_in[3];
    const float* fc1w = (const float*)d_in[4];
    const float* fc1b = (const float*)d_in[5];
    const float* fc2w = (const float*)d_in[6];
    const float* fc2b = (const float*)d_in[7];

    char* ws = (char*)d_ws;
    float* h = (float*)ws;
    size_t off = (size_t)BB * CC * SS * 4;                       // 167.8 MB
    unsigned short* basisT = (unsigned short*)(ws + off); off += (size_t)32 * SS * 2;   // 4 MB
    float* Xp = (float*)(ws + off); off += (size_t)32 * 640 * 32 * 4;                   // 2.6 MB
    float* cA = (float*)(ws + off); off += (size_t)BB * CC * NM * 4;
    float* cB = (float*)(ws + off); off += (size_t)BB * CC * NM * 4;
    float* invmax = (float*)(ws + off); off += 256;

    dim3 gBS(SS / 256, BB);

    k_prep<<<1, 256, 0, stream>>>(pd, invmax);
    k_basis<<<SS / 256, 256, 0, stream>>>(basisT);
    k_fc0<<<gBS, 256, 0, stream>>>(x, pd, fc0w, fc0b, invmax, h);

    for (int l = 0; l < 4; ++l) {
        const float* wre = (const float*)d_in[8 + 4 * l];
        const float* wim = (const float*)d_in[9 + 4 * l];
        const float* ww  = (const float*)d_in[10 + 4 * l];
        const float* wb  = (const float*)d_in[11 + 4 * l];
        k_dft<<<dim3(32, 40), 256, 0, stream>>>(h, basisT, Xp);
        k_mix<<<BB, 320, 0, stream>>>(Xp, wre, wim, cA, cB);
        k_point<<<gBS, 256, 0, stream>>>(h, ww, wb, cA, cB, (l < 3) ? 1 : 0);
    }
    k_final<<<gBS, 256, 0, stream>>>(h, fc1w, fc1b, fc2w, fc2b, (float*)d_out);
}

// Round 3
// 1225.188 us; speedup vs baseline: 6.0382x; 2.2044x over previous
//
#include <hip/hip_runtime.h>
#include <math.h>

#define BB 32
#define SS 65536
#define CC 20
#define NM 16
#define HH 128
#define RP 264   // LDS row pitch in bf16 elems: 256 + 8 (breaks row-bank aliasing)

using short8  = __attribute__((ext_vector_type(8))) short;
using floatx4 = __attribute__((ext_vector_type(4))) float;

__device__ __forceinline__ unsigned short f2bf(float f) {
    union { float f; unsigned u; } v; v.f = f;
    unsigned u = v.u;
    return (unsigned short)((u + 0x7FFFu + ((u >> 16) & 1u)) >> 16);   // RNE
}

// ---------------- k_prep: 1/max(point_data) + zero cP accumulators ----------
// grid 321: block 0 = max-reduce, blocks 1..320 zero cP (4*32*640 floats)
__global__ __launch_bounds__(256) void k_prep(const float* __restrict__ pd,
                                              float* __restrict__ invmax,
                                              float* __restrict__ cP) {
    if (blockIdx.x == 0) {
        __shared__ float red[256];
        int t = threadIdx.x;
        float m = -1e30f;
        for (int i = t; i < SS; i += 256) m = fmaxf(m, pd[i]);
        red[t] = m; __syncthreads();
        for (int off = 128; off > 0; off >>= 1) {
            if (t < off) red[t] = fmaxf(red[t], red[t + off]);
            __syncthreads();
        }
        if (t == 0) invmax[0] = 1.0f / red[0];
    } else {
        int idx = (blockIdx.x - 1) * 256 + threadIdx.x;   // 320*256 = 81920 = 4*32*640
        cP[idx] = 0.0f;
    }
}

// ---------------- shared DFT tail: LDS-staged MFMA partial DFT --------------
// sh_hA: bf16 h rows [32][RP] (rows >= CC zeroed), sh_ph: phasor rows
// (0..15 cos, 16..31 sin). Accumulates P/Q partials into cPdst[cs*320+o*16+m]
// via device-scope atomics. Lane mapping matches R0's validated k_dft.
__device__ __forceinline__ void dft_phase(unsigned short* sh_hA, unsigned short* sh_ph,
                                          int tid, float* cPdst) {
    int wave = tid >> 6, lane = tid & 63;
    int quad = lane >> 4, frow = lane & 15;
    floatx4 acc00 = {0.f,0.f,0.f,0.f}, acc01 = {0.f,0.f,0.f,0.f};
    floatx4 acc10 = {0.f,0.f,0.f,0.f}, acc11 = {0.f,0.f,0.f,0.f};
    int kb = wave * 64 + quad * 8;
    #pragma unroll
    for (int kc = 0; kc < 2; ++kc) {
        int k = kb + kc * 32;
        short8 a0 = *(const short8*)(sh_hA + frow * RP + k);
        short8 a1 = *(const short8*)(sh_hA + (16 + frow) * RP + k);
        short8 bc = *(const short8*)(sh_ph + frow * RP + k);
        short8 bs = *(const short8*)(sh_ph + (16 + frow) * RP + k);
        acc00 = __builtin_amdgcn_mfma_f32_16x16x32_bf16(a0, bc, acc00, 0, 0, 0);
        acc01 = __builtin_amdgcn_mfma_f32_16x16x32_bf16(a0, bs, acc01, 0, 0, 0);
        acc10 = __builtin_amdgcn_mfma_f32_16x16x32_bf16(a1, bc, acc10, 0, 0, 0);
        acc11 = __builtin_amdgcn_mfma_f32_16x16x32_bf16(a1, bs, acc11, 0, 0, 0);
    }
    __syncthreads();                       // all LDS reads done; reuse hA as red
    float* red = (float*)sh_hA;            // 4 waves * 4 frags * 4 regs * 64 = 16 KB
    #pragma unroll
    for (int r = 0; r < 4; ++r) {
        red[wave * 1024 + 0 * 256 + r * 64 + lane] = acc00[r];
        red[wave * 1024 + 1 * 256 + r * 64 + lane] = acc01[r];
        red[wave * 1024 + 2 * 256 + r * 64 + lane] = acc10[r];
        red[wave * 1024 + 3 * 256 + r * 64 + lane] = acc11[r];
    }
    __syncthreads();
    #pragma unroll
    for (int ii = 0; ii < 4; ++ii) {
        int idx = ii * 256 + tid;
        float v = red[idx] + red[1024 + idx] + red[2048 + idx] + red[3072 + idx];
        int f = idx >> 8;                       // rowgroup*2 + cs
        int r = (idx >> 6) & 3, ln = idx & 63;
        int o = (f >> 1) * 16 + (ln >> 4) * 4 + r;   // D row = quad*4+reg
        int m = ln & 15;                              // D col = lane&15
        if (o < CC) atomicAdd(cPdst + (f & 1) * 320 + o * 16 + m, v);
    }
}

// ---------------- k_fc0_dft: h[b][c][s] = fc0(x,grid); + DFT partials -------
__global__ __launch_bounds__(256, 2) void k_fc0_dft(const float* __restrict__ x,
        const float* __restrict__ pd, const float* __restrict__ w,
        const float* __restrict__ bias, const float* __restrict__ invmax,
        float* __restrict__ h, float* __restrict__ cP0) {
    __shared__ __align__(16) unsigned short sh_hA[32 * RP];
    __shared__ __align__(16) unsigned short sh_ph[32 * RP];
    __shared__ float lw[2 * CC], lb[CC];
    int tid = threadIdx.x;
    if (tid < 2 * CC) lw[tid] = w[tid];
    if (tid < CC) lb[tid] = bias[tid];
    {   // zero pad rows CC..31
        unsigned* z = (unsigned*)(sh_hA + CC * RP);
        for (int i = tid; i < (32 - CC) * RP / 2; i += 256) z[i] = 0;
    }
    __syncthreads();
    int b = blockIdx.y;
    int s = blockIdx.x * 256 + tid;
    float xv = x[(size_t)b * SS + s];
    float g  = pd[s] * invmax[0];
    float* hp = h + (size_t)b * CC * SS + s;
    // phasors theta_m = 2*pi*m*s/S
    float u = (float)s * (1.0f / 32768.0f);
    float s1, c1; sincospif(u, &s1, &c1);
    float cm = 1.0f, sm = 0.0f;
    #pragma unroll
    for (int m = 0; m < NM; ++m) {
        sh_ph[m * RP + tid]        = f2bf(cm);
        sh_ph[(16 + m) * RP + tid] = f2bf(sm);
        float cn = cm * c1 - sm * s1;
        sm = sm * c1 + cm * s1;
        cm = cn;
    }
    #pragma unroll
    for (int c = 0; c < CC; ++c) {
        float v = xv * lw[c] + g * lw[CC + c] + lb[c];
        hp[(size_t)c * SS] = v;
        sh_hA[c * RP + tid] = f2bf(v);
    }
    __syncthreads();
    dft_phase(sh_hA, sh_ph, tid, cP0 + (size_t)b * 640);
}

// ---------------- k_point_dft: h=act(spectral+conv+bias) in place; + DFT ----
// flags: bit0 = gelu, bit1 = compute DFT partials for the next layer
__global__ __launch_bounds__(256, 2) void k_point_dft(float* __restrict__ h,
        const float* __restrict__ ww, const float* __restrict__ wb,
        const float* __restrict__ cA, const float* __restrict__ cB,
        float* __restrict__ cPn, int flags) {
    __shared__ __align__(16) unsigned short sh_hA[32 * RP];
    __shared__ __align__(16) unsigned short sh_ph[32 * RP];
    __shared__ float lww[CC * CC], lwb[CC], lA[CC * NM], lB[CC * NM];
    int tid = threadIdx.x;
    int b = blockIdx.y;
    for (int i = tid; i < CC * CC; i += 256) lww[i] = ww[i];
    if (tid < CC) lwb[tid] = wb[tid];
    for (int i = tid; i < CC * NM; i += 256) { lA[i] = cA[b * CC * NM + i]; lB[i] = cB[b * CC * NM + i]; }
    int do_dft = flags & 2;        // kernel-arg: block-uniform branches only
    if (do_dft) {
        unsigned* z = (unsigned*)(sh_hA + CC * RP);
        for (int i = tid; i < (32 - CC) * RP / 2; i += 256) z[i] = 0;
    }
    __syncthreads();
    int s = blockIdx.x * 256 + tid;
    float* hp = h + (size_t)b * CC * SS + s;
    float u = (float)s * (1.0f / 32768.0f);
    float s1, c1; sincospif(u, &s1, &c1);
    float cm[NM], sm[NM];
    cm[0] = 1.0f; sm[0] = 0.0f;
    #pragma unroll
    for (int m = 1; m < NM; ++m) {
        cm[m] = cm[m - 1] * c1 - sm[m - 1] * s1;
        sm[m] = sm[m - 1] * c1 + cm[m - 1] * s1;
    }
    if (do_dft) {
        #pragma unroll
        for (int m = 0; m < NM; ++m) {
            sh_ph[m * RP + tid]        = f2bf(cm[m]);
            sh_ph[(16 + m) * RP + tid] = f2bf(sm[m]);
        }
    }
    float hv[CC];
    #pragma unroll
    for (int c = 0; c < CC; ++c) hv[c] = hp[(size_t)c * SS];
    int gel = flags & 1;
    #pragma unroll 2
    for (int o = 0; o < CC; ++o) {
        float a = lwb[o];
        #pragma unroll
        for (int c = 0; c < CC; ++c) a += lww[o * CC + c] * hv[c];
        #pragma unroll
        for (int m = 0; m < NM; ++m)
            a += lA[o * NM + m] * cm[m] + lB[o * NM + m] * sm[m];
        if (gel) a = 0.5f * a * (1.0f + erff(a * 0.7071067811865476f));
        hp[(size_t)o * SS] = a;
        if (do_dft) sh_hA[o * RP + tid] = f2bf(a);
    }
    if (do_dft) {
        __syncthreads();
        dft_phase(sh_hA, sh_ph, tid, cPn + (size_t)b * 640);
    }
}

// ---------------- k_mix: cP -> complex mixing -> irfft coefs ---------------
__global__ __launch_bounds__(320) void k_mix(const float* __restrict__ cP,
                                             const float* __restrict__ wre, const float* __restrict__ wim,
                                             float* __restrict__ cA, float* __restrict__ cB) {
    int b = blockIdx.x, tid = threadIdx.x;
    __shared__ float PQ[640];                  // [i][col]: col<16 P(cos), >=16 Q(sin)
    const float* base = cP + (size_t)b * 640;
    int i = tid >> 4, m = tid & 15;
    PQ[i * 32 + m]      = base[tid];           // cs=0
    PQ[i * 32 + 16 + m] = base[320 + tid];     // cs=1
    __syncthreads();
    int o = i;
    float reY = 0.f, imY = 0.f;
    #pragma unroll
    for (int c = 0; c < CC; ++c) {
        float P = PQ[c * 32 + m], Q = PQ[c * 32 + 16 + m];
        float wr = wre[(size_t)(c * CC + o) * NM + m];
        float wi = wim[(size_t)(c * CC + o) * NM + m];
        reY += P * wr + Q * wi;                // X = P - iQ
        imY += P * wi - Q * wr;
    }
    const float invS = 1.0f / (float)SS;
    float a, bb;
    if (m == 0) { a = reY * invS; bb = 0.0f; } // irfft drops Im(DC)
    else        { a = 2.0f * reY * invS; bb = -2.0f * imY * invS; }
    cA[(size_t)(b * CC + o) * NM + m] = a;
    cB[(size_t)(b * CC + o) * NM + m] = bb;
}

// ---------------- k_final: fc1 + gelu + fc2 ----------------
__global__ __launch_bounds__(256) void k_final(const float* __restrict__ h,
                                               const float* __restrict__ w1, const float* __restrict__ b1,
                                               const float* __restrict__ w2, const float* __restrict__ b2,
                                               float* __restrict__ out) {
    __shared__ float lw1[CC * HH], lb1[HH], lw2[HH];
    int tid = threadIdx.x;
    for (int i = tid; i < CC * HH; i += 256) lw1[i] = w1[i];
    if (tid < HH) { lb1[tid] = b1[tid]; lw2[tid] = w2[tid]; }
    __syncthreads();
    int b = blockIdx.y;
    int s = blockIdx.x * 256 + tid;
    const float* hp = h + (size_t)b * CC * SS + s;
    float hv[CC];
    #pragma unroll
    for (int c = 0; c < CC; ++c) hv[c] = hp[(size_t)c * SS];
    float acc = b2[0];
    for (int j = 0; j < HH; ++j) {
        float t = lb1[j];
        #pragma unroll
        for (int c = 0; c < CC; ++c) t += hv[c] * lw1[c * HH + j];
        t = 0.5f * t * (1.0f + erff(t * 0.7071067811865476f));
        acc += t * lw2[j];
    }
    out[(size_t)b * SS + s] = acc;
}

extern "C" void kernel_launch(void* const* d_in, const int* in_sizes, int n_in,
                              void* d_out, int out_size, void* d_ws, size_t ws_size,
                              hipStream_t stream) {
    (void)in_sizes; (void)n_in; (void)out_size; (void)ws_size;
    const float* x    = (const float*)d_in[0];
    const float* pd   = (const float*)d_in[1];
    const float* fc0w = (const float*)d_in[2];
    const float* fc0b = (const float*)d_in[3];
    const float* fc1w = (const float*)d_in[4];
    const float* fc1b = (const float*)d_in[5];
    const float* fc2w = (const float*)d_in[6];
    const float* fc2b = (const float*)d_in[7];

    char* ws = (char*)d_ws;
    float* h = (float*)ws;
    size_t off = (size_t)BB * CC * SS * 4;                         // 167.8 MB
    float* cP = (float*)(ws + off); off += (size_t)4 * BB * 640 * 4;  // 327 KB, 4 DFT slots
    float* cA = (float*)(ws + off); off += (size_t)BB * CC * NM * 4;
    float* cB = (float*)(ws + off); off += (size_t)BB * CC * NM * 4;
    float* invmax = (float*)(ws + off); off += 256;

    dim3 gBS(SS / 256, BB);

    k_prep<<<321, 256, 0, stream>>>(pd, invmax, cP);
    k_fc0_dft<<<gBS, 256, 0, stream>>>(x, pd, fc0w, fc0b, invmax, h, cP);

    for (int l = 0; l < 4; ++l) {
        const float* wre = (const float*)d_in[8 + 4 * l];
        const float* wim = (const float*)d_in[9 + 4 * l];
        const float* ww  = (const float*)d_in[10 + 4 * l];
        const float* wb  = (const float*)d_in[11 + 4 * l];
        k_mix<<<BB, 320, 0, stream>>>(cP + (size_t)l * BB * 640, wre, wim, cA, cB);
        int flags = (l < 3) ? 3 : 0;   // gelu+dft for 0..2; layer 3: neither
        float* cPn = (l < 3) ? (cP + (size_t)(l + 1) * BB * 640) : (float*)nullptr;
        k_point_dft<<<gBS, 256, 0, stream>>>(h, ww, wb, cA, cB, cPn, flags);
    }
    k_final<<<gBS, 256, 0, stream>>>(h, fc1w, fc1b, fc2w, fc2b, (float*)d_out);
}

// Round 4
// 1115.343 us; speedup vs baseline: 6.6329x; 1.0985x over previous
//
#include <hip/hip_runtime.h>
#include <math.h>

#define BB 32
#define SS 65536
#define CC 20
#define NM 16
#define HH 128
#define RP 264   // DFT LDS row pitch (bf16 elems)
#define WP 72    // transposed-tile row pitch (bf16 elems): 64 + 8 pad -> 2-way-free

using short8  = __attribute__((ext_vector_type(8))) short;
using floatx4 = __attribute__((ext_vector_type(4))) float;

__device__ __forceinline__ unsigned short f2bf(float f) {
    union { float f; unsigned u; } v; v.f = f;
    unsigned u = v.u;
    return (unsigned short)((u + 0x7FFFu + ((u >> 16) & 1u)) >> 16);   // RNE
}
__device__ __forceinline__ float bf2f(unsigned short h) {
    union { unsigned u; float f; } v; v.u = ((unsigned)h) << 16; return v.f;
}

// ---------------- k_prep: 1/max(point_data) + zero cP accumulators ----------
__global__ __launch_bounds__(256) void k_prep(const float* __restrict__ pd,
                                              float* __restrict__ invmax,
                                              float* __restrict__ cP) {
    if (blockIdx.x == 0) {
        __shared__ float red[256];
        int t = threadIdx.x;
        float m = -1e30f;
        for (int i = t; i < SS; i += 256) m = fmaxf(m, pd[i]);
        red[t] = m; __syncthreads();
        for (int off = 128; off > 0; off >>= 1) {
            if (t < off) red[t] = fmaxf(red[t], red[t + off]);
            __syncthreads();
        }
        if (t == 0) invmax[0] = 1.0f / red[0];
    } else {
        int idx = (blockIdx.x - 1) * 256 + threadIdx.x;   // 320*256 = 4*32*640
        cP[idx] = 0.0f;
    }
}

// ---------------- shared DFT tail: LDS-staged MFMA partial DFT --------------
__device__ __forceinline__ void dft_phase(unsigned short* sh_hA, unsigned short* sh_ph,
                                          int tid, float* cPdst) {
    int wave = tid >> 6, lane = tid & 63;
    int quad = lane >> 4, frow = lane & 15;
    floatx4 acc00 = {0.f,0.f,0.f,0.f}, acc01 = {0.f,0.f,0.f,0.f};
    floatx4 acc10 = {0.f,0.f,0.f,0.f}, acc11 = {0.f,0.f,0.f,0.f};
    int kb = wave * 64 + quad * 8;
    #pragma unroll
    for (int kc = 0; kc < 2; ++kc) {
        int k = kb + kc * 32;
        short8 a0 = *(const short8*)(sh_hA + frow * RP + k);
        short8 a1 = *(const short8*)(sh_hA + (16 + frow) * RP + k);
        short8 bc = *(const short8*)(sh_ph + frow * RP + k);
        short8 bs = *(const short8*)(sh_ph + (16 + frow) * RP + k);
        acc00 = __builtin_amdgcn_mfma_f32_16x16x32_bf16(a0, bc, acc00, 0, 0, 0);
        acc01 = __builtin_amdgcn_mfma_f32_16x16x32_bf16(a0, bs, acc01, 0, 0, 0);
        acc10 = __builtin_amdgcn_mfma_f32_16x16x32_bf16(a1, bc, acc10, 0, 0, 0);
        acc11 = __builtin_amdgcn_mfma_f32_16x16x32_bf16(a1, bs, acc11, 0, 0, 0);
    }
    __syncthreads();
    float* red = (float*)sh_hA;
    #pragma unroll
    for (int r = 0; r < 4; ++r) {
        red[wave * 1024 + 0 * 256 + r * 64 + lane] = acc00[r];
        red[wave * 1024 + 1 * 256 + r * 64 + lane] = acc01[r];
        red[wave * 1024 + 2 * 256 + r * 64 + lane] = acc10[r];
        red[wave * 1024 + 3 * 256 + r * 64 + lane] = acc11[r];
    }
    __syncthreads();
    #pragma unroll
    for (int ii = 0; ii < 4; ++ii) {
        int idx = ii * 256 + tid;
        float v = red[idx] + red[1024 + idx] + red[2048 + idx] + red[3072 + idx];
        int f = idx >> 8;
        int r = (idx >> 6) & 3, ln = idx & 63;
        int o = (f >> 1) * 16 + (ln >> 4) * 4 + r;   // D row = quad*4+reg
        int m = ln & 15;                              // D col = lane&15
        if (o < CC) atomicAdd(cPdst + (f & 1) * 320 + o * 16 + m, v);
    }
}

// ---------------- k_fc0_dft ----------------
__global__ __launch_bounds__(256, 4) void k_fc0_dft(const float* __restrict__ x,
        const float* __restrict__ pd, const float* __restrict__ w,
        const float* __restrict__ bias, const float* __restrict__ invmax,
        float* __restrict__ h, float* __restrict__ cP0) {
    __shared__ __align__(16) unsigned short sh_hA[32 * RP];
    __shared__ __align__(16) unsigned short sh_ph[32 * RP];
    __shared__ float lw[2 * CC], lb[CC];
    int tid = threadIdx.x;
    if (tid < 2 * CC) lw[tid] = w[tid];
    if (tid < CC) lb[tid] = bias[tid];
    {
        unsigned* z = (unsigned*)(sh_hA + CC * RP);
        for (int i = tid; i < (32 - CC) * RP / 2; i += 256) z[i] = 0;
    }
    __syncthreads();
    int b = blockIdx.y;
    int s = blockIdx.x * 256 + tid;
    float xv = x[(size_t)b * SS + s];
    float g  = pd[s] * invmax[0];
    float* hp = h + (size_t)b * CC * SS + s;
    float u = (float)s * (1.0f / 32768.0f);
    float s1, c1; sincospif(u, &s1, &c1);
    float cm = 1.0f, sm = 0.0f;
    #pragma unroll
    for (int m = 0; m < NM; ++m) {
        sh_ph[m * RP + tid]        = f2bf(cm);
        sh_ph[(16 + m) * RP + tid] = f2bf(sm);
        float cn = cm * c1 - sm * s1;
        sm = sm * c1 + cm * s1;
        cm = cn;
    }
    #pragma unroll
    for (int c = 0; c < CC; ++c) {
        float v = xv * lw[c] + g * lw[CC + c] + lb[c];
        hp[(size_t)c * SS] = v;
        sh_hA[c * RP + tid] = f2bf(v);
    }
    __syncthreads();
    dft_phase(sh_hA, sh_ph, tid, cP0 + (size_t)b * 640);
}

// ---------------- k_point_dft ----------------
__global__ __launch_bounds__(256, 3) void k_point_dft(float* __restrict__ h,
        const float* __restrict__ ww, const float* __restrict__ wb,
        const float* __restrict__ cA, const float* __restrict__ cB,
        float* __restrict__ cPn, int flags) {
    __shared__ __align__(16) unsigned short sh_hA[32 * RP];
    __shared__ __align__(16) unsigned short sh_ph[32 * RP];
    __shared__ float lww[CC * CC], lwb[CC], lA[CC * NM], lB[CC * NM];
    int tid = threadIdx.x;
    int b = blockIdx.y;
    for (int i = tid; i < CC * CC; i += 256) lww[i] = ww[i];
    if (tid < CC) lwb[tid] = wb[tid];
    for (int i = tid; i < CC * NM; i += 256) { lA[i] = cA[b * CC * NM + i]; lB[i] = cB[b * CC * NM + i]; }
    int do_dft = flags & 2;
    if (do_dft) {
        unsigned* z = (unsigned*)(sh_hA + CC * RP);
        for (int i = tid; i < (32 - CC) * RP / 2; i += 256) z[i] = 0;
    }
    __syncthreads();
    int s = blockIdx.x * 256 + tid;
    float* hp = h + (size_t)b * CC * SS + s;
    float u = (float)s * (1.0f / 32768.0f);
    float s1, c1; sincospif(u, &s1, &c1);
    float cm[NM], sm[NM];
    cm[0] = 1.0f; sm[0] = 0.0f;
    #pragma unroll
    for (int m = 1; m < NM; ++m) {
        cm[m] = cm[m - 1] * c1 - sm[m - 1] * s1;
        sm[m] = sm[m - 1] * c1 + cm[m - 1] * s1;
    }
    if (do_dft) {
        #pragma unroll
        for (int m = 0; m < NM; ++m) {
            sh_ph[m * RP + tid]        = f2bf(cm[m]);
            sh_ph[(16 + m) * RP + tid] = f2bf(sm[m]);
        }
    }
    float hv[CC];
    #pragma unroll
    for (int c = 0; c < CC; ++c) hv[c] = hp[(size_t)c * SS];
    int gel = flags & 1;
    #pragma unroll 2
    for (int o = 0; o < CC; ++o) {
        float a = lwb[o];
        #pragma unroll
        for (int c = 0; c < CC; ++c) a += lww[o * CC + c] * hv[c];
        #pragma unroll
        for (int m = 0; m < NM; ++m)
            a += lA[o * NM + m] * cm[m] + lB[o * NM + m] * sm[m];
        if (gel) a = 0.5f * a * (1.0f + erff(a * 0.7071067811865476f));
        hp[(size_t)o * SS] = a;
        if (do_dft) sh_hA[o * RP + tid] = f2bf(a);
    }
    if (do_dft) {
        __syncthreads();
        dft_phase(sh_hA, sh_ph, tid, cPn + (size_t)b * 640);
    }
}

// ---------------- k_mix ----------------
__global__ __launch_bounds__(320) void k_mix(const float* __restrict__ cP,
                                             const float* __restrict__ wre, const float* __restrict__ wim,
                                             float* __restrict__ cA, float* __restrict__ cB) {
    int b = blockIdx.x, tid = threadIdx.x;
    __shared__ float PQ[640];
    const float* base = cP + (size_t)b * 640;
    int i = tid >> 4, m = tid & 15;
    PQ[i * 32 + m]      = base[tid];
    PQ[i * 32 + 16 + m] = base[320 + tid];
    __syncthreads();
    int o = i;
    float reY = 0.f, imY = 0.f;
    #pragma unroll
    for (int c = 0; c < CC; ++c) {
        float P = PQ[c * 32 + m], Q = PQ[c * 32 + 16 + m];
        float wr = wre[(size_t)(c * CC + o) * NM + m];
        float wi = wim[(size_t)(c * CC + o) * NM + m];
        reY += P * wr + Q * wi;
        imY += P * wi - Q * wr;
    }
    const float invS = 1.0f / (float)SS;
    float a, bb;
    if (m == 0) { a = reY * invS; bb = 0.0f; }
    else        { a = 2.0f * reY * invS; bb = -2.0f * imY * invS; }
    cA[(size_t)(b * CC + o) * NM + m] = a;
    cB[(size_t)(b * CC + o) * NM + m] = bb;
}

// ---------------- k_final: MFMA fc1 (bf16 hi/lo split) + gelu + fc2 ---------
// Block: 256 thr / 4 waves, 128 s. hT LDS [s][c]: hi c 0..19, lo 32..51, pads 0.
// w1T LDS [j][c]: same col layout. Wave w: s rows w*32..w*32+31 (2 m-tiles).
__global__ __launch_bounds__(256, 2) void k_final(const float* __restrict__ h,
                                               const float* __restrict__ w1, const float* __restrict__ b1,
                                               const float* __restrict__ w2, const float* __restrict__ b2,
                                               float* __restrict__ out) {
    __shared__ __align__(16) unsigned short hT[128 * WP];
    __shared__ __align__(16) unsigned short w1T[128 * WP];
    __shared__ float lb1[HH], lw2[HH], outS[128];
    int tid = threadIdx.x;
    // zero both transposed tiles (covers the zero-pad columns)
    {
        unsigned* z = (unsigned*)hT;           // hT and w1T are adjacent-ish; zero each
        for (int i = tid; i < 128 * WP / 2; i += 256) z[i] = 0;
        unsigned* z2 = (unsigned*)w1T;
        for (int i = tid; i < 128 * WP / 2; i += 256) z2[i] = 0;
    }
    if (tid < HH) { lb1[tid] = b1[tid]; lw2[tid] = w2[tid]; }
    __syncthreads();
    // stage w1 transposed, hi/lo split
    for (int idx = tid; idx < CC * HH; idx += 256) {
        int c = idx / HH, j = idx - c * HH;           // w1[c][j]
        float v = w1[idx];
        unsigned short hi = f2bf(v);
        float lof = v - bf2f(hi);
        w1T[j * WP + c]      = hi;
        w1T[j * WP + 32 + c] = f2bf(lof);
    }
    // stage h tile transposed, hi/lo split
    int b = blockIdx.y;
    int s0 = blockIdx.x * 128;
    int sl = tid & 127, half = tid >> 7;              // half 0: c 0..9, half 1: c 10..19
    const float* hp = h + (size_t)b * CC * SS + s0 + sl;
    #pragma unroll
    for (int cc = 0; cc < 10; ++cc) {
        int c = half * 10 + cc;
        float v = hp[(size_t)c * SS];
        unsigned short hi = f2bf(v);
        float lof = v - bf2f(hi);
        hT[sl * WP + c]      = hi;
        hT[sl * WP + 32 + c] = f2bf(lof);
    }
    __syncthreads();

    int wave = tid >> 6, lane = tid & 63;
    int col = lane & 15, quad = lane >> 4;
    // B fragments in registers: B[k=quad*8+jj][n=col] = w1[k][nt*16+col]
    short8 bhi[8], blo[8];
    #pragma unroll
    for (int nt = 0; nt < 8; ++nt) {
        bhi[nt] = *(const short8*)(w1T + (nt * 16 + col) * WP + quad * 8);
        blo[nt] = *(const short8*)(w1T + (nt * 16 + col) * WP + 32 + quad * 8);
    }
    float lb1r[8], w2r[8];
    #pragma unroll
    for (int nt = 0; nt < 8; ++nt) { lb1r[nt] = lb1[nt * 16 + col]; w2r[nt] = lw2[nt * 16 + col]; }
    float b2v = b2[0];

    #pragma unroll
    for (int mt = 0; mt < 2; ++mt) {
        int srow = wave * 32 + mt * 16 + col;         // A row m = lane&15
        short8 ahi = *(const short8*)(hT + srow * WP + quad * 8);
        short8 alo = *(const short8*)(hT + srow * WP + 32 + quad * 8);
        floatx4 acc[8];
        #pragma unroll
        for (int nt = 0; nt < 8; ++nt) {
            floatx4 a = {0.f, 0.f, 0.f, 0.f};
            a = __builtin_amdgcn_mfma_f32_16x16x32_bf16(ahi, bhi[nt], a, 0, 0, 0);
            a = __builtin_amdgcn_mfma_f32_16x16x32_bf16(ahi, blo[nt], a, 0, 0, 0);
            a = __builtin_amdgcn_mfma_f32_16x16x32_bf16(alo, bhi[nt], a, 0, 0, 0);
            acc[nt] = a;
        }
        // epilogue: bias + gelu(erf) + fc2 partial
        float part[4] = {0.f, 0.f, 0.f, 0.f};
        #pragma unroll
        for (int nt = 0; nt < 8; ++nt) {
            #pragma unroll
            for (int r = 0; r < 4; ++r) {
                float t = acc[nt][r] + lb1r[nt];
                t = 0.5f * t * (1.0f + erff(t * 0.7071067811865476f));
                part[r] += t * w2r[nt];
            }
        }
        #pragma unroll
        for (int r = 0; r < 4; ++r) {
            float p = part[r];
            p += __shfl_xor(p, 1, 64);
            p += __shfl_xor(p, 2, 64);
            p += __shfl_xor(p, 4, 64);
            p += __shfl_xor(p, 8, 64);
            if (col == 0) outS[wave * 32 + mt * 16 + quad * 4 + r] = p + b2v;
        }
    }
    __syncthreads();
    if (tid < 128) out[(size_t)b * SS + s0 + tid] = outS[tid];
}

extern "C" void kernel_launch(void* const* d_in, const int* in_sizes, int n_in,
                              void* d_out, int out_size, void* d_ws, size_t ws_size,
                              hipStream_t stream) {
    (void)in_sizes; (void)n_in; (void)out_size; (void)ws_size;
    const float* x    = (const float*)d_in[0];
    const float* pd   = (const float*)d_in[1];
    const float* fc0w = (const float*)d_in[2];
    const float* fc0b = (const float*)d_in[3];
    const float* fc1w = (const float*)d_in[4];
    const float* fc1b = (const float*)d_in[5];
    const float* fc2w = (const float*)d_in[6];
    const float* fc2b = (const float*)d_in[7];

    char* ws = (char*)d_ws;
    float* h = (float*)ws;
    size_t off = (size_t)BB * CC * SS * 4;
    float* cP = (float*)(ws + off); off += (size_t)4 * BB * 640 * 4;
    float* cA = (float*)(ws + off); off += (size_t)BB * CC * NM * 4;
    float* cB = (float*)(ws + off); off += (size_t)BB * CC * NM * 4;
    float* invmax = (float*)(ws + off); off += 256;

    dim3 gBS(SS / 256, BB);

    k_prep<<<321, 256, 0, stream>>>(pd, invmax, cP);
    k_fc0_dft<<<gBS, 256, 0, stream>>>(x, pd, fc0w, fc0b, invmax, h, cP);

    for (int l = 0; l < 4; ++l) {
        const float* wre = (const float*)d_in[8 + 4 * l];
        const float* wim = (const float*)d_in[9 + 4 * l];
        const float* ww  = (const float*)d_in[10 + 4 * l];
        const float* wb  = (const float*)d_in[11 + 4 * l];
        k_mix<<<BB, 320, 0, stream>>>(cP + (size_t)l * BB * 640, wre, wim, cA, cB);
        int flags = (l < 3) ? 3 : 0;
        float* cPn = (l < 3) ? (cP + (size_t)(l + 1) * BB * 640) : (float*)nullptr;
        k_point_dft<<<gBS, 256, 0, stream>>>(h, ww, wb, cA, cB, cPn, flags);
    }
    k_final<<<dim3(SS / 128, BB), 256, 0, stream>>>(h, fc1w, fc1b, fc2w, fc2b, (float*)d_out);
}